// Round 3
// baseline (418.712 us; speedup 1.0000x reference)
//
#include <hip/hip_runtime.h>

#define MM    12
#define TSOL  64
#define NXX   256
#define NYY   256
#define NTT   50
#define NOUTT 256

// Stencil coefficient tables over {row[k-1], row[k], row[k+1]}, built per call.
// out_k contribution from source m = A*row[k-1] + B*row[k] + C*row[k+1].
// A[k=0] == 0 and C[k=255] == 0 by construction (iy clamped to [0,254]).
__device__ float g_a[MM * NOUTT];
__device__ float g_b[MM * NOUTT];
__device__ float g_c[MM * NOUTT];

// grid: MM blocks x 256 threads. Block m computes table row m.
__global__ __launch_bounds__(256) void ai_setup_kernel(
    const float* __restrict__ params,
    const float* __restrict__ Wq, const float* __restrict__ bq,
    const float* __restrict__ Wk, const float* __restrict__ bk)
{
    const int k = threadIdx.x;
    const int m = blockIdx.x;

    __shared__ float s_attn[MM][4];
    __shared__ float s_sw[MM];
    __shared__ float s_wm;
    __shared__ float s_ys[NYY];

    if (k < MM) {
        float ly = params[k * 3 + 0];
        float p0 = (ly - 30.0f) / 90.0f;
        float p1 = params[k * 3 + 1] / 0.0029f;
        float p2 = params[k * 3 + 2] / 0.0018f;
        const float t0 = 0.5f;                 // (75-30)/90 exact
        const float t1 = 0.001f / 0.0029f;
        const float t2 = 0.0001f / 0.0018f;
        for (int h = 0; h < 4; ++h) {
            float acc = 0.0f;
            for (int d = 0; d < 8; ++d) {
                int o = h * 8 + d;
                float q  = t0 * Wq[o * 3 + 0] + t1 * Wq[o * 3 + 1] + t2 * Wq[o * 3 + 2] + bq[o];
                float kv = p0 * Wk[o * 3 + 0] + p1 * Wk[o * 3 + 1] + p2 * Wk[o * 3 + 2] + bk[o];
                acc += kv * q;
            }
            s_attn[k][h] = acc * 0.35355339059327373f;  // 1/sqrt(8)
        }
        float d0 = (p0 - t0) / 0.25f;
        float d1 = (p1 - t1) / 0.25f;
        float d2 = (p2 - t2) / 0.25f;
        s_sw[k] = expf(-(d0 * d0 + d1 * d1 + d2 * d2) * 0.5f);
    }
    __syncthreads();

    if (k == 0) {
        float aw[MM];
        for (int j = 0; j < MM; ++j) aw[j] = 0.0f;
        for (int h = 0; h < 4; ++h) {               // softmax over m, per head
            float mx = s_attn[0][h];
            for (int j = 1; j < MM; ++j) mx = fmaxf(mx, s_attn[j][h]);
            float e[MM]; float sum = 0.0f;
            for (int j = 0; j < MM; ++j) { e[j] = expf(s_attn[j][h] - mx); sum += e[j]; }
            for (int j = 0; j < MM; ++j) aw[j] += e[j] / sum;
        }
        float swsum = 0.0f;
        for (int j = 0; j < MM; ++j) swsum += s_sw[j];
        float wj[MM]; float wsum = 0.0f;
        for (int j = 0; j < MM; ++j) {
            wj[j] = (aw[j] * 0.25f) * (s_sw[j] / swsum);
            wsum += wj[j];
        }
        s_wm = wj[m] / wsum;
    }

    // ys row for this m — EXACT fp32 op sequence of the reference:
    // ys[j] = fl( fl(l01[j]*ly) * fl(75/ly) ),  l01[j] = fl(j * fl(1/255))
    {
        float ly  = params[m * 3 + 0];
        float inv = 75.0f / ly;                    // IEEE divide (no fast-math)
        float l01 = (float)k * (1.0f / 255.0f);
        s_ys[k] = (l01 * ly) * inv;
    }
    __syncthreads();

    float w  = s_wm;
    float yq = (float)k * (75.0f / 255.0f);        // rounds to exactly 75.0 at k=255
    // upper_bound: largest j with ys[j] <= yq  (== searchsorted 'right' - 1)
    int l = 0, r = NYY;
    while (l < r) { int mid = (l + r) >> 1; if (s_ys[mid] <= yq) l = mid + 1; else r = mid; }
    int iy = l - 1;
    iy = iy < 0 ? 0 : (iy > NYY - 2 ? NYY - 2 : iy);
    float ty  = (yq - s_ys[iy]) / (s_ys[iy + 1] - s_ys[iy]);
    bool  inb = (yq >= s_ys[0]) && (yq <= s_ys[NYY - 1]);   // the k=255 knife edge
    float w0 = inb ? w * (1.0f - ty) : 0.0f;
    float w1 = inb ? w * ty : 0.0f;
    // iy is guaranteed in {k-1, k} (grid spacing 0.294 >> ulp-scale ys
    // perturbation); encode as 3-point stencil on {k-1, k, k+1}.
    bool sel = (iy == k);
    g_a[m * NOUTT + k] = sel ? 0.0f : w0;
    g_b[m * NOUTT + k] = sel ? w0 : w1;
    g_c[m * NOUTT + k] = sel ? w1 : 0.0f;
}

// grid: (NOUTT/4, NTT), block 256 = 4 waves. Wave w handles output row
// i = blockIdx.x*4 + w: lane l computes k = 4l..4l+3 for both channels.
// Each (m,ch) source row is read exactly once per wave as 64 coalesced
// float4 loads; the k-1 / k+1 stencil halo comes from 2 shuffles.
// No LDS, no barrier — pure load->FMA with compiler-scheduled vmcnt.
__global__ __launch_bounds__(256, 4) void ai_resample_kernel(
    const float* __restrict__ c1, const float* __restrict__ c2,
    float* __restrict__ out)
{
    const int tid  = threadIdx.x;
    const int lane = tid & 63;
    const int wv   = tid >> 6;
    const int t    = blockIdx.y;
    const int i    = blockIdx.x * 4 + wv;
    int tsrc = (t * TSOL) / (NTT - 1);             // floor(t*64/49), fp-robust
    if (tsrc > TSOL - 1) tsrc = TSOL - 1;

    const int kb = lane * 4;                       // first k of this lane's quad
    float4 o1 = make_float4(0.f, 0.f, 0.f, 0.f);
    float4 o2 = make_float4(0.f, 0.f, 0.f, 0.f);

#pragma unroll
    for (int m = 0; m < MM; ++m) {
        const float4 A = *(const float4*)(g_a + m * NOUTT + kb);
        const float4 B = *(const float4*)(g_b + m * NOUTT + kb);
        const float4 C = *(const float4*)(g_c + m * NOUTT + kb);
        size_t base = ((size_t)((m * TSOL + tsrc) * NXX + i)) * NYY + (size_t)kb;
        float4 x = *(const float4*)(c1 + base);
        float4 y = *(const float4*)(c2 + base);
        float xl = __shfl_up(x.w, 1);              // row[4l-1] (lane 0: *0 via A.x==0 at k=0)
        float xr = __shfl_down(x.x, 1);            // row[4l+4] (lane 63: *0 via C.w==0 at k=255)
        float yl = __shfl_up(y.w, 1);
        float yr = __shfl_down(y.x, 1);
        o1.x += A.x * xl  + B.x * x.x + C.x * x.y;
        o1.y += A.y * x.x + B.y * x.y + C.y * x.z;
        o1.z += A.z * x.y + B.z * x.z + C.z * x.w;
        o1.w += A.w * x.z + B.w * x.w + C.w * xr;
        o2.x += A.x * yl  + B.x * y.x + C.x * y.y;
        o2.y += A.y * y.x + B.y * y.y + C.y * y.z;
        o2.z += A.z * y.y + B.z * y.z + C.z * y.w;
        o2.w += A.w * y.z + B.w * y.w + C.w * yr;
    }

    if (lane == 0)  o1.x = 0.001f;                 // c1[:, :, 0]  = C_CU_TARGET
    if (lane == 63) o2.w = 0.0001f;                // c2[:, :, -1] = C_NI_TARGET

    size_t ob = ((size_t)t * NOUTT + (size_t)i) * NOUTT + (size_t)kb;
    *(float4*)(out + ob) = o1;
    *(float4*)(out + (size_t)NTT * NOUTT * NOUTT + ob) = o2;
}

extern "C" void kernel_launch(void* const* d_in, const int* in_sizes, int n_in,
                              void* d_out, int out_size, void* d_ws, size_t ws_size,
                              hipStream_t stream) {
    const float* params = (const float*)d_in[0];
    const float* c1     = (const float*)d_in[1];
    const float* c2     = (const float*)d_in[2];
    const float* Wq     = (const float*)d_in[3];
    const float* bq     = (const float*)d_in[4];
    const float* Wk     = (const float*)d_in[5];
    const float* bk     = (const float*)d_in[6];
    float* out = (float*)d_out;

    ai_setup_kernel<<<dim3(MM), dim3(256), 0, stream>>>(params, Wq, bq, Wk, bk);
    ai_resample_kernel<<<dim3(NOUTT / 4, NTT), dim3(256), 0, stream>>>(c1, c2, out);
}